// Round 4
// baseline (533.221 us; speedup 1.0000x reference)
//
#include <hip/hip_runtime.h>

// GCN 2-layer, N=200000, E=3200000.
// R2/R3 evidence: atomic passes are bound by per-64B-line serialized RMWs
// (~635 ns each, chain = atomics/line = 256 -> ~162 us regardless of width).
// Fix: pad every accumulator to its own 64B cache line.
//   deg_pad / outacc_pad: 1 counter per line  -> chain 16 (avg in-degree)
//   acc_pad:  one node's 4 floats per line    -> chain 64
// Also keeps the linearity trick: aggregate x*dinv (4-dim), apply W1 after.

#define PAD 16  // 16 x 4B = 64B line per node slot

__global__ void k_degree(const int* __restrict__ dst, int E, int* __restrict__ deg_pad) {
    int i = blockIdx.x * blockDim.x + threadIdx.x;
    if (i < E) atomicAdd(&deg_pad[(long long)dst[i] * PAD], 1);
}

// Per node: dinv, x_scaled = x*dinv (float4).
__global__ void k_node1(const float* __restrict__ x, const int* __restrict__ deg_pad,
                        float* __restrict__ dinv, float* __restrict__ x_scaled, int N) {
    int i = blockIdx.x * blockDim.x + threadIdx.x;
    if (i >= N) return;
    float d = (float)(deg_pad[(long long)i * PAD] + 1);   // +1: self loop
    float di = 1.0f / sqrtf(d);
    dinv[i] = di;
    float4 xv = ((const float4*)x)[i];
    ((float4*)x_scaled)[i] = make_float4(xv.x * di, xv.y * di, xv.z * di, xv.w * di);
}

// 4 lanes per edge: acc_pad[dst*PAD + j] += x_scaled[src*4 + j]
__global__ void k_scatter1(const int* __restrict__ src, const int* __restrict__ dst,
                           const float* __restrict__ x_scaled,
                           float* __restrict__ acc_pad, long long T) {
    long long t = (long long)blockIdx.x * blockDim.x + threadIdx.x;
    if (t >= T) return;
    int e = (int)(t >> 2);
    int j = (int)(t & 3);
    atomicAdd(&acc_pad[(long long)dst[e] * PAD + j], x_scaled[(long long)src[e] * 4 + j]);
}

// Per node: agg = acc_pad + x_scaled (self loop); pre = di*agg;
// h1 = relu(pre@W1 + b1); z = h1@W2; z_scaled = z*di.
__global__ void k_node2(const float* __restrict__ acc_pad, const float* __restrict__ x_scaled,
                        const float* __restrict__ dinv,
                        const float* __restrict__ W1, const float* __restrict__ b1,
                        const float* __restrict__ W2,
                        float* __restrict__ z_scaled, int N) {
    int i = blockIdx.x * blockDim.x + threadIdx.x;
    if (i >= N) return;
    float di = dinv[i];
    const float* a = &acc_pad[(long long)i * PAD];
    float4 xs = ((const float4*)x_scaled)[i];
    float p0 = di * (a[0] + xs.x);
    float p1 = di * (a[1] + xs.y);
    float p2 = di * (a[2] + xs.z);
    float p3 = di * (a[3] + xs.w);
    float z = 0.0f;
    #pragma unroll
    for (int c = 0; c < 16; ++c) {
        float h1 = p0 * W1[0 * 16 + c] + p1 * W1[1 * 16 + c]
                 + p2 * W1[2 * 16 + c] + p3 * W1[3 * 16 + c] + b1[c];
        h1 = fmaxf(h1, 0.0f);
        z += h1 * W2[c];
    }
    z_scaled[i] = z * di;
}

// 1 thread per edge: outacc_pad[dst*PAD] += z_scaled[src]
__global__ void k_scatter2(const int* __restrict__ src, const int* __restrict__ dst,
                           const float* __restrict__ z_scaled,
                           float* __restrict__ outacc_pad, int E) {
    int e = blockIdx.x * blockDim.x + threadIdx.x;
    if (e < E)
        atomicAdd(&outacc_pad[(long long)dst[e] * PAD], z_scaled[src[e]]);
}

// out[i] = di*(edge_sum + z_scaled[i]) + b2   (self loop: z*di^2 = z_scaled*di)
__global__ void k_final(const float* __restrict__ outacc_pad, const float* __restrict__ z_scaled,
                        const float* __restrict__ dinv, const float* __restrict__ b2,
                        float* __restrict__ out, int N) {
    int i = blockIdx.x * blockDim.x + threadIdx.x;
    if (i >= N) return;
    out[i] = dinv[i] * (outacc_pad[(long long)i * PAD] + z_scaled[i]) + b2[0];
}

extern "C" void kernel_launch(void* const* d_in, const int* in_sizes, int n_in,
                              void* d_out, int out_size, void* d_ws, size_t ws_size,
                              hipStream_t stream) {
    const float* x  = (const float*)d_in[0];
    const int*   ei = (const int*)d_in[1];   // [2, E] as int32
    const float* W1 = (const float*)d_in[2];
    const float* b1 = (const float*)d_in[3];
    const float* W2 = (const float*)d_in[4];
    const float* b2 = (const float*)d_in[5];

    const int N = in_sizes[0] / 4;
    const int E = in_sizes[1] / 2;
    const int* src = ei;
    const int* dst = ei + E;

    // Workspace (30.4 MB): dinv[N] | z_scaled[N] | x_scaled[N*4] |
    //   acc_pad[N*PAD] | deg_pad/outacc_pad[N*PAD] (aliased: deg consumed by
    //   k_node1 before the region is re-zeroed for the layer-2 accumulator)
    char* ws = (char*)d_ws;
    float* dinv     = (float*)ws;  ws += (size_t)N * 4;
    float* z_scaled = (float*)ws;  ws += (size_t)N * 4;
    float* x_scaled = (float*)ws;  ws += (size_t)N * 4 * 4;
    float* acc_pad  = (float*)ws;  ws += (size_t)N * PAD * 4;
    int*   deg_pad  = (int*)ws;    // aliased:
    float* outacc_pad = (float*)deg_pad;
    float* out = (float*)d_out;

    const int B = 256;
    const size_t padBytes = (size_t)N * PAD * 4;

    hipMemsetAsync(deg_pad, 0, padBytes, stream);
    hipMemsetAsync(acc_pad, 0, padBytes, stream);
    k_degree<<<(E + B - 1) / B, B, 0, stream>>>(dst, E, deg_pad);
    k_node1<<<(N + B - 1) / B, B, 0, stream>>>(x, deg_pad, dinv, x_scaled, N);
    long long T = (long long)E * 4;
    k_scatter1<<<(int)((T + B - 1) / B), B, 0, stream>>>(src, dst, x_scaled, acc_pad, T);
    k_node2<<<(N + B - 1) / B, B, 0, stream>>>(acc_pad, x_scaled, dinv, W1, b1, W2,
                                               z_scaled, N);
    hipMemsetAsync(outacc_pad, 0, padBytes, stream);  // deg_pad already consumed
    k_scatter2<<<(E + B - 1) / B, B, 0, stream>>>(src, dst, z_scaled, outacc_pad, E);
    k_final<<<(N + B - 1) / B, B, 0, stream>>>(outacc_pad, z_scaled, dinv, b2, out, N);
}

// Round 5
// 255.535 us; speedup vs baseline: 2.0867x; 2.0867x over previous
//
#include <hip/hip_runtime.h>

// GCN 2-layer, N=200000, E=3200000.
// R2-R4 evidence: device-scope atomic passes cost ~50ns per atomic LINE
// transaction (~20G/s chip-wide) regardless of count/padding/contention.
// => eliminate global atomics: bucket-sort edges by dst (256-node buckets),
// aggregate with LDS atomics, write results with coalesced stores.

#define BS   256    // block size
#define NA   1024   // edge-chunk blocks for hist/bin passes
#define NBP  784    // compile-time bucket capacity (stride); runtime nb=782

// Pass A1: per-block bucket histogram (LDS), write blockHist[b][*].
__global__ void k_hist(const int* __restrict__ dst, int E, int chunk,
                       unsigned* __restrict__ blockHist) {
    __shared__ unsigned h[NBP];
    for (int i = threadIdx.x; i < NBP; i += BS) h[i] = 0;
    __syncthreads();
    int b = blockIdx.x;
    int lo = b * chunk, hi = min(E, lo + chunk);
    for (int e = lo + threadIdx.x; e < hi; e += BS)
        atomicAdd(&h[((unsigned)dst[e]) >> 8], 1u);
    __syncthreads();
    for (int i = threadIdx.x; i < NBP; i += BS)
        blockHist[(size_t)b * NBP + i] = h[i];
}

// Pass A2a: per bucket k, exclusive scan of blockHist[0..NA-1][k] over blocks.
__global__ void k_scan_col(const unsigned* __restrict__ blockHist,
                           unsigned* __restrict__ blockOfs,
                           unsigned* __restrict__ total) {
    int k = blockIdx.x, t = threadIdx.x;
    unsigned v[4], s = 0;
    #pragma unroll
    for (int i = 0; i < 4; ++i) {
        v[i] = blockHist[(size_t)(4 * t + i) * NBP + k];
        s += v[i];
    }
    __shared__ unsigned sums[BS];
    sums[t] = s;
    __syncthreads();
    for (int off = 1; off < BS; off <<= 1) {       // inclusive scan (double-sync)
        unsigned x = (t >= off) ? sums[t - off] : 0;
        __syncthreads();
        sums[t] += x;
        __syncthreads();
    }
    unsigned run = sums[t] - s;                    // exclusive prefix for this thread
    #pragma unroll
    for (int i = 0; i < 4; ++i) {
        blockOfs[(size_t)(4 * t + i) * NBP + k] = run;
        run += v[i];
    }
    if (t == BS - 1) total[k] = sums[t];
}

// Pass A2b: exclusive scan of bucket totals -> base[0..nb], base[nb]=E.
__global__ void k_scan_base(const unsigned* __restrict__ total,
                            unsigned* __restrict__ base, int nb) {
    __shared__ unsigned s[1024];
    int t = threadIdx.x;
    unsigned v = (t < nb) ? total[t] : 0;
    s[t] = v;
    __syncthreads();
    for (int off = 1; off < 1024; off <<= 1) {
        unsigned x = (t >= off) ? s[t - off] : 0;
        __syncthreads();
        s[t] += x;
        __syncthreads();
    }
    if (t < nb) base[t] = s[t] - v;
    if (t == nb - 1) base[nb] = s[t];
}

// Pass A3: scatter packed edges into bucket segments (plain stores).
__global__ void k_bin(const int* __restrict__ src, const int* __restrict__ dst,
                      int E, int chunk,
                      const unsigned* __restrict__ base,
                      const unsigned* __restrict__ blockOfs,
                      unsigned* __restrict__ epack) {
    __shared__ unsigned cur[NBP];
    int b = blockIdx.x;
    for (int i = threadIdx.x; i < NBP; i += BS)
        cur[i] = base[i] + blockOfs[(size_t)b * NBP + i];
    __syncthreads();
    int lo = b * chunk, hi = min(E, lo + chunk);
    for (int e = lo + threadIdx.x; e < hi; e += BS) {
        unsigned d = (unsigned)dst[e];
        unsigned k = d >> 8;
        unsigned pos = atomicAdd(&cur[k], 1u);     // LDS cursor
        epack[pos] = ((unsigned)src[e] << 8) | (d & 255u);
    }
}

// Pass B1: per-bucket in-degree (LDS) -> dinv; fused x_scaled = x*dinv.
__global__ void k_deg(const unsigned* __restrict__ epack, const unsigned* __restrict__ base,
                      const float* __restrict__ x,
                      float* __restrict__ dinv, float* __restrict__ x_scaled, int N) {
    __shared__ unsigned cnt[BS];
    int k = blockIdx.x, t = threadIdx.x;
    cnt[t] = 0;
    __syncthreads();
    unsigned lo = base[k], hi = base[k + 1];
    for (unsigned i = lo + t; i < hi; i += BS)
        atomicAdd(&cnt[epack[i] & 255u], 1u);
    __syncthreads();
    int node = k * 256 + t;
    if (node < N) {
        float di = rsqrtf((float)(cnt[t] + 1));    // +1: self loop
        dinv[node] = di;
        float4 xv = ((const float4*)x)[node];
        ((float4*)x_scaled)[node] = make_float4(xv.x * di, xv.y * di, xv.z * di, xv.w * di);
    }
}

// Pass B2: aggregate x_scaled[src] per dst (LDS), fused layer-1+layer-2 node math.
// acc layout [j][256] so each atomic instr spreads banks by dlo (conflict-light).
__global__ void k_agg1(const unsigned* __restrict__ epack, const unsigned* __restrict__ base,
                       const float* __restrict__ x_scaled, const float* __restrict__ dinv,
                       const float* __restrict__ W1, const float* __restrict__ b1,
                       const float* __restrict__ W2,
                       float* __restrict__ z_scaled, int N) {
    __shared__ float acc[4 * BS];
    int k = blockIdx.x, t = threadIdx.x;
    #pragma unroll
    for (int j = 0; j < 4; ++j) acc[j * BS + t] = 0.0f;
    __syncthreads();
    unsigned lo = base[k], hi = base[k + 1];
    for (unsigned i = lo + t; i < hi; i += BS) {
        unsigned p = epack[i];
        unsigned s = p >> 8, dlo = p & 255u;
        float4 xs = ((const float4*)x_scaled)[s];
        atomicAdd(&acc[0 * BS + dlo], xs.x);
        atomicAdd(&acc[1 * BS + dlo], xs.y);
        atomicAdd(&acc[2 * BS + dlo], xs.z);
        atomicAdd(&acc[3 * BS + dlo], xs.w);
    }
    __syncthreads();
    int node = k * 256 + t;
    if (node < N) {
        float di = dinv[node];
        float4 xs = ((const float4*)x_scaled)[node];      // self loop
        float p0 = di * (acc[0 * BS + t] + xs.x);
        float p1 = di * (acc[1 * BS + t] + xs.y);
        float p2 = di * (acc[2 * BS + t] + xs.z);
        float p3 = di * (acc[3 * BS + t] + xs.w);
        float z = 0.0f;
        #pragma unroll
        for (int c = 0; c < 16; ++c) {
            float h1 = p0 * W1[0 * 16 + c] + p1 * W1[1 * 16 + c]
                     + p2 * W1[2 * 16 + c] + p3 * W1[3 * 16 + c] + b1[c];
            h1 = fmaxf(h1, 0.0f);
            z += h1 * W2[c];
        }
        z_scaled[node] = z * di;
    }
}

// Pass C: aggregate z_scaled[src] per dst (LDS), final output.
__global__ void k_agg2(const unsigned* __restrict__ epack, const unsigned* __restrict__ base,
                       const float* __restrict__ z_scaled, const float* __restrict__ dinv,
                       const float* __restrict__ b2, float* __restrict__ out, int N) {
    __shared__ float acc[BS];
    int k = blockIdx.x, t = threadIdx.x;
    acc[t] = 0.0f;
    __syncthreads();
    unsigned lo = base[k], hi = base[k + 1];
    for (unsigned i = lo + t; i < hi; i += BS) {
        unsigned p = epack[i];
        atomicAdd(&acc[p & 255u], z_scaled[p >> 8]);
    }
    __syncthreads();
    int node = k * 256 + t;
    if (node < N)
        out[node] = dinv[node] * (acc[t] + z_scaled[node]) + b2[0];
}

extern "C" void kernel_launch(void* const* d_in, const int* in_sizes, int n_in,
                              void* d_out, int out_size, void* d_ws, size_t ws_size,
                              hipStream_t stream) {
    const float* x  = (const float*)d_in[0];
    const int*   ei = (const int*)d_in[1];   // [2, E] as int32
    const float* W1 = (const float*)d_in[2];
    const float* b1 = (const float*)d_in[3];
    const float* W2 = (const float*)d_in[4];
    const float* b2 = (const float*)d_in[5];

    const int N = in_sizes[0] / 4;
    const int E = in_sizes[1] / 2;
    const int* src = ei;
    const int* dst = ei + E;
    const int nb = (N + 255) / 256;          // 782 (must be <= NBP and <= 1024)
    const int chunk = (E + NA - 1) / NA;

    // Workspace (~24 MB): blockHist[NA*NBP] | blockOfs[NA*NBP] | total[NBP] |
    //   base[NBP+1] | epack[E] | dinv[N] | x_scaled[N*4] | z_scaled[N]
    char* ws = (char*)d_ws;
    unsigned* blockHist = (unsigned*)ws;  ws += (size_t)NA * NBP * 4;
    unsigned* blockOfs  = (unsigned*)ws;  ws += (size_t)NA * NBP * 4;
    unsigned* total     = (unsigned*)ws;  ws += (size_t)NBP * 4;
    unsigned* base      = (unsigned*)ws;  ws += (size_t)(NBP + 1) * 4;
    unsigned* epack     = (unsigned*)ws;  ws += (size_t)E * 4;
    float*    dinv      = (float*)ws;     ws += (size_t)N * 4;
    float*    x_scaled  = (float*)ws;     ws += (size_t)N * 4 * 4;
    float*    z_scaled  = (float*)ws;     ws += (size_t)N * 4;
    float* out = (float*)d_out;

    k_hist     <<<NA, BS, 0, stream>>>(dst, E, chunk, blockHist);
    k_scan_col <<<nb, BS, 0, stream>>>(blockHist, blockOfs, total);
    k_scan_base<<<1, 1024, 0, stream>>>(total, base, nb);
    k_bin      <<<NA, BS, 0, stream>>>(src, dst, E, chunk, base, blockOfs, epack);
    k_deg      <<<nb, BS, 0, stream>>>(epack, base, x, dinv, x_scaled, N);
    k_agg1     <<<nb, BS, 0, stream>>>(epack, base, x_scaled, dinv, W1, b1, W2, z_scaled, N);
    k_agg2     <<<nb, BS, 0, stream>>>(epack, base, z_scaled, dinv, b2, out, N);
}

// Round 6
// 242.297 us; speedup vs baseline: 2.2007x; 1.0546x over previous
//
#include <hip/hip_runtime.h>

// GCN 2-layer, N=200000, E=3200000.
// R5 evidence: bucket/LDS-atomic pipeline works (255us), but edge-pass kernels
// are latency-bound at 21% occupancy with MLP=1.
// R6: BS=1024 (32 waves/CU resident) + x4 stride-unroll (4 gathers in flight).

#define BS   1024   // block size for edge passes
#define CH   4096   // edge chunk per hist/bin block
#define NBP  784    // bucket capacity stride (runtime nb = 782)

// Pass A1: per-block bucket histogram (LDS) over an edge chunk.
__global__ void k_hist(const int* __restrict__ dst, int E,
                       unsigned* __restrict__ blockHist) {
    __shared__ unsigned h[NBP];
    for (int i = threadIdx.x; i < NBP; i += BS) h[i] = 0;
    __syncthreads();
    int b = blockIdx.x, t = threadIdx.x;
    int lo = b * CH, hi = min(E, lo + CH);
    int i = lo + t;
    for (; i + 3 * BS < hi; i += 4 * BS) {
        unsigned d0 = (unsigned)dst[i], d1 = (unsigned)dst[i + BS];
        unsigned d2 = (unsigned)dst[i + 2 * BS], d3 = (unsigned)dst[i + 3 * BS];
        atomicAdd(&h[d0 >> 8], 1u); atomicAdd(&h[d1 >> 8], 1u);
        atomicAdd(&h[d2 >> 8], 1u); atomicAdd(&h[d3 >> 8], 1u);
    }
    for (; i < hi; i += BS) atomicAdd(&h[((unsigned)dst[i]) >> 8], 1u);
    __syncthreads();
    for (int j = threadIdx.x; j < NBP; j += BS)
        blockHist[(size_t)b * NBP + j] = h[j];
}

// Pass A2a: per bucket k, exclusive scan over the NA chunk-blocks.
__global__ void k_scan_col(const unsigned* __restrict__ blockHist,
                           unsigned* __restrict__ blockOfs,
                           unsigned* __restrict__ total, int NA) {
    int k = blockIdx.x, t = threadIdx.x;           // 256 threads
    unsigned v[4], s = 0;
    #pragma unroll
    for (int i = 0; i < 4; ++i) {
        int blk = 4 * t + i;
        v[i] = (blk < NA) ? blockHist[(size_t)blk * NBP + k] : 0;
        s += v[i];
    }
    __shared__ unsigned sums[256];
    sums[t] = s;
    __syncthreads();
    for (int off = 1; off < 256; off <<= 1) {
        unsigned x = (t >= off) ? sums[t - off] : 0;
        __syncthreads();
        sums[t] += x;
        __syncthreads();
    }
    unsigned run = sums[t] - s;
    #pragma unroll
    for (int i = 0; i < 4; ++i) {
        int blk = 4 * t + i;
        if (blk < NA) blockOfs[(size_t)blk * NBP + k] = run;
        run += v[i];
    }
    if (t == 255) total[k] = sums[t];
}

// Pass A2b: exclusive scan of bucket totals -> base[0..nb], base[nb]=E.
__global__ void k_scan_base(const unsigned* __restrict__ total,
                            unsigned* __restrict__ base, int nb) {
    __shared__ unsigned s[1024];
    int t = threadIdx.x;
    unsigned v = (t < nb) ? total[t] : 0;
    s[t] = v;
    __syncthreads();
    for (int off = 1; off < 1024; off <<= 1) {
        unsigned x = (t >= off) ? s[t - off] : 0;
        __syncthreads();
        s[t] += x;
        __syncthreads();
    }
    if (t < nb) base[t] = s[t] - v;
    if (t == nb - 1) base[nb] = s[t];
}

// Pass A3: scatter packed edges into bucket segments (plain stores, LDS cursors).
__global__ void k_bin(const int* __restrict__ src, const int* __restrict__ dst,
                      int E, const unsigned* __restrict__ base,
                      const unsigned* __restrict__ blockOfs,
                      unsigned* __restrict__ epack) {
    __shared__ unsigned cur[NBP];
    int b = blockIdx.x, t = threadIdx.x;
    for (int i = t; i < NBP; i += BS)
        cur[i] = base[i] + blockOfs[(size_t)b * NBP + i];
    __syncthreads();
    int lo = b * CH, hi = min(E, lo + CH);
    int i = lo + t;
    for (; i + 3 * BS < hi; i += 4 * BS) {
        unsigned d0 = (unsigned)dst[i], d1 = (unsigned)dst[i + BS];
        unsigned d2 = (unsigned)dst[i + 2 * BS], d3 = (unsigned)dst[i + 3 * BS];
        unsigned s0 = (unsigned)src[i], s1 = (unsigned)src[i + BS];
        unsigned s2 = (unsigned)src[i + 2 * BS], s3 = (unsigned)src[i + 3 * BS];
        unsigned p0 = atomicAdd(&cur[d0 >> 8], 1u);
        unsigned p1 = atomicAdd(&cur[d1 >> 8], 1u);
        unsigned p2 = atomicAdd(&cur[d2 >> 8], 1u);
        unsigned p3 = atomicAdd(&cur[d3 >> 8], 1u);
        epack[p0] = (s0 << 8) | (d0 & 255u);
        epack[p1] = (s1 << 8) | (d1 & 255u);
        epack[p2] = (s2 << 8) | (d2 & 255u);
        epack[p3] = (s3 << 8) | (d3 & 255u);
    }
    for (; i < hi; i += BS) {
        unsigned d = (unsigned)dst[i];
        unsigned pos = atomicAdd(&cur[d >> 8], 1u);
        epack[pos] = ((unsigned)src[i] << 8) | (d & 255u);
    }
}

// Pass B1: per-bucket in-degree (LDS) -> dinv; fused x_scaled = x*dinv.
__global__ void k_deg(const unsigned* __restrict__ epack, const unsigned* __restrict__ base,
                      const float* __restrict__ x,
                      float* __restrict__ dinv, float* __restrict__ x_scaled, int N) {
    __shared__ unsigned cnt[256];
    int k = blockIdx.x, t = threadIdx.x;
    for (int i = t; i < 256; i += BS) cnt[i] = 0;
    __syncthreads();
    unsigned lo = base[k], hi = base[k + 1];
    unsigned i = lo + t;
    for (; i + 3u * BS < hi; i += 4u * BS) {
        unsigned p0 = epack[i], p1 = epack[i + BS];
        unsigned p2 = epack[i + 2 * BS], p3 = epack[i + 3 * BS];
        atomicAdd(&cnt[p0 & 255u], 1u); atomicAdd(&cnt[p1 & 255u], 1u);
        atomicAdd(&cnt[p2 & 255u], 1u); atomicAdd(&cnt[p3 & 255u], 1u);
    }
    for (; i < hi; i += BS) atomicAdd(&cnt[epack[i] & 255u], 1u);
    __syncthreads();
    int node = k * 256 + t;
    if (t < 256 && node < N) {
        float di = rsqrtf((float)(cnt[t] + 1));    // +1: self loop
        dinv[node] = di;
        float4 xv = ((const float4*)x)[node];
        ((float4*)x_scaled)[node] = make_float4(xv.x * di, xv.y * di, xv.z * di, xv.w * di);
    }
}

// Pass B2: aggregate x_scaled[src] per dst (LDS), fused layer1+layer2 node math.
__global__ void k_agg1(const unsigned* __restrict__ epack, const unsigned* __restrict__ base,
                       const float* __restrict__ x_scaled, const float* __restrict__ dinv,
                       const float* __restrict__ W1, const float* __restrict__ b1,
                       const float* __restrict__ W2,
                       float* __restrict__ z_scaled, int N) {
    __shared__ float acc[4 * 256];
    int k = blockIdx.x, t = threadIdx.x;
    for (int i = t; i < 4 * 256; i += BS) acc[i] = 0.0f;
    __syncthreads();
    unsigned lo = base[k], hi = base[k + 1];
    const float4* xs4 = (const float4*)x_scaled;
    unsigned i = lo + t;
    for (; i + 3u * BS < hi; i += 4u * BS) {
        unsigned p0 = epack[i], p1 = epack[i + BS];
        unsigned p2 = epack[i + 2 * BS], p3 = epack[i + 3 * BS];
        float4 a0 = xs4[p0 >> 8], a1 = xs4[p1 >> 8];
        float4 a2 = xs4[p2 >> 8], a3 = xs4[p3 >> 8];
        unsigned d0 = p0 & 255u, d1 = p1 & 255u, d2 = p2 & 255u, d3 = p3 & 255u;
        atomicAdd(&acc[0 * 256 + d0], a0.x); atomicAdd(&acc[1 * 256 + d0], a0.y);
        atomicAdd(&acc[2 * 256 + d0], a0.z); atomicAdd(&acc[3 * 256 + d0], a0.w);
        atomicAdd(&acc[0 * 256 + d1], a1.x); atomicAdd(&acc[1 * 256 + d1], a1.y);
        atomicAdd(&acc[2 * 256 + d1], a1.z); atomicAdd(&acc[3 * 256 + d1], a1.w);
        atomicAdd(&acc[0 * 256 + d2], a2.x); atomicAdd(&acc[1 * 256 + d2], a2.y);
        atomicAdd(&acc[2 * 256 + d2], a2.z); atomicAdd(&acc[3 * 256 + d2], a2.w);
        atomicAdd(&acc[0 * 256 + d3], a3.x); atomicAdd(&acc[1 * 256 + d3], a3.y);
        atomicAdd(&acc[2 * 256 + d3], a3.z); atomicAdd(&acc[3 * 256 + d3], a3.w);
    }
    for (; i < hi; i += BS) {
        unsigned p = epack[i];
        float4 a = xs4[p >> 8];
        unsigned d = p & 255u;
        atomicAdd(&acc[0 * 256 + d], a.x); atomicAdd(&acc[1 * 256 + d], a.y);
        atomicAdd(&acc[2 * 256 + d], a.z); atomicAdd(&acc[3 * 256 + d], a.w);
    }
    __syncthreads();
    int node = k * 256 + t;
    if (t < 256 && node < N) {
        float di = dinv[node];
        float4 xs = xs4[node];                      // self loop
        float p0 = di * (acc[0 * 256 + t] + xs.x);
        float p1 = di * (acc[1 * 256 + t] + xs.y);
        float p2 = di * (acc[2 * 256 + t] + xs.z);
        float p3 = di * (acc[3 * 256 + t] + xs.w);
        float z = 0.0f;
        #pragma unroll
        for (int c = 0; c < 16; ++c) {
            float h1 = p0 * W1[0 * 16 + c] + p1 * W1[1 * 16 + c]
                     + p2 * W1[2 * 16 + c] + p3 * W1[3 * 16 + c] + b1[c];
            h1 = fmaxf(h1, 0.0f);
            z += h1 * W2[c];
        }
        z_scaled[node] = z * di;
    }
}

// Pass C: aggregate z_scaled[src] per dst (LDS), final output.
__global__ void k_agg2(const unsigned* __restrict__ epack, const unsigned* __restrict__ base,
                       const float* __restrict__ z_scaled, const float* __restrict__ dinv,
                       const float* __restrict__ b2, float* __restrict__ out, int N) {
    __shared__ float acc[256];
    int k = blockIdx.x, t = threadIdx.x;
    for (int i = t; i < 256; i += BS) acc[i] = 0.0f;
    __syncthreads();
    unsigned lo = base[k], hi = base[k + 1];
    unsigned i = lo + t;
    for (; i + 3u * BS < hi; i += 4u * BS) {
        unsigned p0 = epack[i], p1 = epack[i + BS];
        unsigned p2 = epack[i + 2 * BS], p3 = epack[i + 3 * BS];
        float v0 = z_scaled[p0 >> 8], v1 = z_scaled[p1 >> 8];
        float v2 = z_scaled[p2 >> 8], v3 = z_scaled[p3 >> 8];
        atomicAdd(&acc[p0 & 255u], v0); atomicAdd(&acc[p1 & 255u], v1);
        atomicAdd(&acc[p2 & 255u], v2); atomicAdd(&acc[p3 & 255u], v3);
    }
    for (; i < hi; i += BS) {
        unsigned p = epack[i];
        atomicAdd(&acc[p & 255u], z_scaled[p >> 8]);
    }
    __syncthreads();
    int node = k * 256 + t;
    if (t < 256 && node < N)
        out[node] = dinv[node] * (acc[t] + z_scaled[node]) + b2[0];
}

extern "C" void kernel_launch(void* const* d_in, const int* in_sizes, int n_in,
                              void* d_out, int out_size, void* d_ws, size_t ws_size,
                              hipStream_t stream) {
    const float* x  = (const float*)d_in[0];
    const int*   ei = (const int*)d_in[1];   // [2, E] as int32
    const float* W1 = (const float*)d_in[2];
    const float* b1 = (const float*)d_in[3];
    const float* W2 = (const float*)d_in[4];
    const float* b2 = (const float*)d_in[5];

    const int N = in_sizes[0] / 4;
    const int E = in_sizes[1] / 2;
    const int* src = ei;
    const int* dst = ei + E;
    const int nb = (N + 255) / 256;          // 782
    const int NA = (E + CH - 1) / CH;        // 782 chunk-blocks

    // Workspace (~22.5 MB): blockHist[NA*NBP] | blockOfs[NA*NBP] | total[NBP] |
    //   base[NBP+1] | epack[E] | dinv[N] | x_scaled[N*4] | z_scaled[N]
    char* ws = (char*)d_ws;
    unsigned* blockHist = (unsigned*)ws;  ws += (size_t)NA * NBP * 4;
    unsigned* blockOfs  = (unsigned*)ws;  ws += (size_t)NA * NBP * 4;
    unsigned* total     = (unsigned*)ws;  ws += (size_t)NBP * 4;
    unsigned* base      = (unsigned*)ws;  ws += (size_t)(NBP + 1) * 4;
    unsigned* epack     = (unsigned*)ws;  ws += (size_t)E * 4;
    float*    dinv      = (float*)ws;     ws += (size_t)N * 4;
    float*    x_scaled  = (float*)ws;     ws += (size_t)N * 4 * 4;
    float*    z_scaled  = (float*)ws;     ws += (size_t)N * 4;
    float* out = (float*)d_out;

    k_hist     <<<NA, BS, 0, stream>>>(dst, E, blockHist);
    k_scan_col <<<nb, 256, 0, stream>>>(blockHist, blockOfs, total, NA);
    k_scan_base<<<1, 1024, 0, stream>>>(total, base, nb);
    k_bin      <<<NA, BS, 0, stream>>>(src, dst, E, base, blockOfs, epack);
    k_deg      <<<nb, BS, 0, stream>>>(epack, base, x, dinv, x_scaled, N);
    k_agg1     <<<nb, BS, 0, stream>>>(epack, base, x_scaled, dinv, W1, b1, W2, z_scaled, N);
    k_agg2     <<<nb, BS, 0, stream>>>(epack, base, z_scaled, dinv, b2, out, N);
}

// Round 7
// 204.252 us; speedup vs baseline: 2.6106x; 1.1863x over previous
//
#include <hip/hip_runtime.h>

// GCN 2-layer, N=200000, E=3200000.
// R5/R6 evidence: LDS atomicAdd retires ~1 lane-op/cycle/CU (k_agg1's 12.8M
// lane-atomics = 50K/CU = 91us; invariant to occupancy/MLP; k_agg2 at 1/4 the
// atomics is ~4x faster with identical gather count).
// R7: full sort-by-dst (bucket bin + in-bucket LDS counting sort) -> CSR,
// then PULL-mode aggregation with zero atomics.

#define BS   1024   // block size, edge chunk passes
#define CH   8192   // edges per hist/bin block
#define NBP  784    // bucket stride (runtime nb = 782)
#define CAP  6656   // max bucket segment staged in LDS (mean 4096, +40 sigma)

// A1: per-chunk bucket histogram (LDS).
__global__ void k_hist(const int* __restrict__ dst, int E,
                       unsigned* __restrict__ blockHist) {
    __shared__ unsigned h[NBP];
    for (int i = threadIdx.x; i < NBP; i += BS) h[i] = 0;
    __syncthreads();
    int b = blockIdx.x, t = threadIdx.x;
    int lo = b * CH, hi = min(E, lo + CH);
    for (int i = lo + t; i < hi; i += BS)
        atomicAdd(&h[((unsigned)dst[i]) >> 8], 1u);
    __syncthreads();
    for (int j = threadIdx.x; j < NBP; j += BS)
        blockHist[(size_t)b * NBP + j] = h[j];
}

// A2a: per bucket k, exclusive scan over the NA chunk-blocks.
__global__ void k_scan_col(const unsigned* __restrict__ blockHist,
                           unsigned* __restrict__ blockOfs,
                           unsigned* __restrict__ total, int NA) {
    int k = blockIdx.x, t = threadIdx.x;           // 256 threads
    unsigned v[4], s = 0;
    #pragma unroll
    for (int i = 0; i < 4; ++i) {
        int blk = 4 * t + i;
        v[i] = (blk < NA) ? blockHist[(size_t)blk * NBP + k] : 0;
        s += v[i];
    }
    __shared__ unsigned sums[256];
    sums[t] = s;
    __syncthreads();
    for (int off = 1; off < 256; off <<= 1) {
        unsigned x = (t >= off) ? sums[t - off] : 0;
        __syncthreads();
        sums[t] += x;
        __syncthreads();
    }
    unsigned run = sums[t] - s;
    #pragma unroll
    for (int i = 0; i < 4; ++i) {
        int blk = 4 * t + i;
        if (blk < NA) blockOfs[(size_t)blk * NBP + k] = run;
        run += v[i];
    }
    if (t == 255) total[k] = sums[t];
}

// A2b: exclusive scan of bucket totals -> base[0..nb], base[nb]=E.
__global__ void k_scan_base(const unsigned* __restrict__ total,
                            unsigned* __restrict__ base, int nb) {
    __shared__ unsigned s[1024];
    int t = threadIdx.x;
    unsigned v = (t < nb) ? total[t] : 0;
    s[t] = v;
    __syncthreads();
    for (int off = 1; off < 1024; off <<= 1) {
        unsigned x = (t >= off) ? s[t - off] : 0;
        __syncthreads();
        s[t] += x;
        __syncthreads();
    }
    if (t < nb) base[t] = s[t] - v;
    if (t == nb - 1) base[nb] = s[t];
}

// A3: scatter packed (src<<8|dlo) into bucket segments (plain stores).
__global__ void k_bin(const int* __restrict__ src, const int* __restrict__ dst,
                      int E, const unsigned* __restrict__ base,
                      const unsigned* __restrict__ blockOfs,
                      unsigned* __restrict__ epack) {
    __shared__ unsigned cur[NBP];
    int b = blockIdx.x, t = threadIdx.x;
    for (int i = t; i < NBP; i += BS)
        cur[i] = base[i] + blockOfs[(size_t)b * NBP + i];
    __syncthreads();
    int lo = b * CH, hi = min(E, lo + CH);
    for (int i = lo + t; i < hi; i += BS) {
        unsigned d = (unsigned)dst[i];
        unsigned pos = atomicAdd(&cur[d >> 8], 1u);
        epack[pos] = ((unsigned)src[i] << 8) | (d & 255u);
    }
}

// B: per bucket — stage segment in LDS, count per node, scan -> rowofs,
// counting-sort the segment in place (epack[lo..hi) becomes sorted src),
// and emit dinv / x_scaled.
__global__ void k_build(unsigned* __restrict__ epack, const unsigned* __restrict__ base,
                        const float* __restrict__ x,
                        float* __restrict__ dinv, float* __restrict__ x_scaled,
                        unsigned* __restrict__ rowofs, int N) {
    __shared__ unsigned stage[CAP];
    __shared__ unsigned cnt[256];
    __shared__ unsigned sc[256];
    __shared__ unsigned cur[256];
    int k = blockIdx.x, t = threadIdx.x;           // 256 threads
    unsigned lo = base[k], hi = base[k + 1];
    int len = (int)(hi - lo);                       // <= CAP for this dataset
    for (int i = t; i < len; i += 256) stage[i] = epack[lo + i];
    cnt[t] = 0;
    __syncthreads();
    for (int i = t; i < len; i += 256) atomicAdd(&cnt[stage[i] & 255u], 1u);
    __syncthreads();
    sc[t] = cnt[t];
    __syncthreads();
    for (int off = 1; off < 256; off <<= 1) {
        unsigned v = (t >= off) ? sc[t - off] : 0;
        __syncthreads();
        sc[t] += v;
        __syncthreads();
    }
    unsigned excl = sc[t] - cnt[t];
    cur[t] = excl;
    int node = k * 256 + t;
    if (node <= N) rowofs[node] = lo + excl;       // node==N lands at E
    if (node < N) {
        float di = rsqrtf((float)(cnt[t] + 1));    // +1: self loop
        dinv[node] = di;
        float4 xv = ((const float4*)x)[node];
        ((float4*)x_scaled)[node] = make_float4(xv.x * di, xv.y * di, xv.z * di, xv.w * di);
    }
    __syncthreads();
    for (int i = t; i < len; i += 256) {
        unsigned p = stage[i];
        unsigned pos = atomicAdd(&cur[p & 255u], 1u);
        epack[lo + pos] = p >> 8;                  // sorted src, in place (safe: all
    }                                              // reads went through LDS stage)
}

// C1: pull-mode layer-1 aggregation + fused node math (no atomics).
__global__ void k_agg1(const unsigned* __restrict__ esorted, const unsigned* __restrict__ rowofs,
                       const float* __restrict__ x_scaled, const float* __restrict__ dinv,
                       const float* __restrict__ W1, const float* __restrict__ b1,
                       const float* __restrict__ W2,
                       float* __restrict__ z_scaled, int N) {
    int node = blockIdx.x * blockDim.x + threadIdx.x;
    if (node >= N) return;
    unsigned lo = rowofs[node], hi = rowofs[node + 1];
    const float4* xs4 = (const float4*)x_scaled;
    float4 a0 = xs4[node];                          // self loop
    float4 a1 = make_float4(0.f, 0.f, 0.f, 0.f);
    unsigned i = lo;
    for (; i + 1 < hi; i += 2) {                    // 2 independent chains
        unsigned s0 = esorted[i], s1 = esorted[i + 1];
        float4 v0 = xs4[s0], v1 = xs4[s1];
        a0.x += v0.x; a0.y += v0.y; a0.z += v0.z; a0.w += v0.w;
        a1.x += v1.x; a1.y += v1.y; a1.z += v1.z; a1.w += v1.w;
    }
    if (i < hi) {
        float4 v = xs4[esorted[i]];
        a0.x += v.x; a0.y += v.y; a0.z += v.z; a0.w += v.w;
    }
    float di = dinv[node];
    float p0 = di * (a0.x + a1.x);
    float p1 = di * (a0.y + a1.y);
    float p2 = di * (a0.z + a1.z);
    float p3 = di * (a0.w + a1.w);
    float z = 0.0f;
    #pragma unroll
    for (int c = 0; c < 16; ++c) {
        float h1 = p0 * W1[0 * 16 + c] + p1 * W1[1 * 16 + c]
                 + p2 * W1[2 * 16 + c] + p3 * W1[3 * 16 + c] + b1[c];
        h1 = fmaxf(h1, 0.0f);
        z += h1 * W2[c];
    }
    z_scaled[node] = z * di;
}

// C2: pull-mode layer-2 aggregation (no atomics).
__global__ void k_agg2(const unsigned* __restrict__ esorted, const unsigned* __restrict__ rowofs,
                       const float* __restrict__ z_scaled, const float* __restrict__ dinv,
                       const float* __restrict__ b2, float* __restrict__ out, int N) {
    int node = blockIdx.x * blockDim.x + threadIdx.x;
    if (node >= N) return;
    unsigned lo = rowofs[node], hi = rowofs[node + 1];
    float a0 = z_scaled[node];                      // self loop
    float a1 = 0.0f;
    unsigned i = lo;
    for (; i + 1 < hi; i += 2) {
        float v0 = z_scaled[esorted[i]], v1 = z_scaled[esorted[i + 1]];
        a0 += v0; a1 += v1;
    }
    if (i < hi) a0 += z_scaled[esorted[i]];
    out[node] = dinv[node] * (a0 + a1) + b2[0];
}

extern "C" void kernel_launch(void* const* d_in, const int* in_sizes, int n_in,
                              void* d_out, int out_size, void* d_ws, size_t ws_size,
                              hipStream_t stream) {
    const float* x  = (const float*)d_in[0];
    const int*   ei = (const int*)d_in[1];   // [2, E] as int32
    const float* W1 = (const float*)d_in[2];
    const float* b1 = (const float*)d_in[3];
    const float* W2 = (const float*)d_in[4];
    const float* b2 = (const float*)d_in[5];

    const int N = in_sizes[0] / 4;
    const int E = in_sizes[1] / 2;
    const int* src = ei;
    const int* dst = ei + E;
    const int nb = (N + 255) / 256;          // 782
    const int NA = (E + CH - 1) / CH;        // 391

    // Workspace (~21 MB): blockHist[NA*NBP] | blockOfs[NA*NBP] | total[NBP] |
    //   base[NBP+1] | epack[E] | rowofs[N+1] | dinv[N] | x_scaled[N*4] | z_scaled[N]
    char* ws = (char*)d_ws;
    unsigned* blockHist = (unsigned*)ws;  ws += (size_t)NA * NBP * 4;
    unsigned* blockOfs  = (unsigned*)ws;  ws += (size_t)NA * NBP * 4;
    unsigned* total     = (unsigned*)ws;  ws += (size_t)NBP * 4;
    unsigned* base      = (unsigned*)ws;  ws += (size_t)(NBP + 1) * 4;
    unsigned* epack     = (unsigned*)ws;  ws += (size_t)E * 4;
    unsigned* rowofs    = (unsigned*)ws;  ws += (size_t)(N + 1) * 4;
    float*    dinv      = (float*)ws;     ws += (size_t)N * 4;
    float*    x_scaled  = (float*)ws;     ws += (size_t)N * 4 * 4;
    float*    z_scaled  = (float*)ws;     ws += (size_t)N * 4;
    float* out = (float*)d_out;

    k_hist     <<<NA, BS, 0, stream>>>(dst, E, blockHist);
    k_scan_col <<<nb, 256, 0, stream>>>(blockHist, blockOfs, total, NA);
    k_scan_base<<<1, 1024, 0, stream>>>(total, base, nb);
    k_bin      <<<NA, BS, 0, stream>>>(src, dst, E, base, blockOfs, epack);
    k_build    <<<nb, 256, 0, stream>>>(epack, base, x, dinv, x_scaled, rowofs, N);
    k_agg1     <<<nb, 256, 0, stream>>>(epack, rowofs, x_scaled, dinv, W1, b1, W2, z_scaled, N);
    k_agg2     <<<nb, 256, 0, stream>>>(epack, rowofs, z_scaled, dinv, b2, out, N);
}

// Round 8
// 199.071 us; speedup vs baseline: 2.6785x; 1.0260x over previous
//
#include <hip/hip_runtime.h>

// GCN 2-layer, N=200000, E=3200000.
// R7 evidence: k_bin write-amplified 4.7x (60MB for 12.8MB epack) because 782
// open cursors x 64 resident blocks/XCD = 3.2MB of active write lines ~ L2
// size -> partial-line evictions. R8: 512-node buckets (nb=391) halve the
// cursor working set (1.6MB << 4MB L2) and double run length to 21 edges.

#define BS    1024  // block size, edge chunk passes
#define CH    8192  // edges per hist/bin block
#define NBW   512   // nodes per bucket
#define SH    9     // log2(NBW)
#define NBP   392   // bucket stride (runtime nb = 391)
#define CAP   9216  // max bucket segment staged in LDS (mean 8192, +11 sigma)

// A1: per-chunk bucket histogram (LDS).
__global__ void k_hist(const int* __restrict__ dst, int E,
                       unsigned* __restrict__ blockHist) {
    __shared__ unsigned h[NBP];
    for (int i = threadIdx.x; i < NBP; i += BS) h[i] = 0;
    __syncthreads();
    int b = blockIdx.x, t = threadIdx.x;
    int lo = b * CH, hi = min(E, lo + CH);
    for (int i = lo + t; i < hi; i += BS)
        atomicAdd(&h[((unsigned)dst[i]) >> SH], 1u);
    __syncthreads();
    for (int j = threadIdx.x; j < NBP; j += BS)
        blockHist[(size_t)b * NBP + j] = h[j];
}

// A2a: per bucket k, exclusive scan over the NA chunk-blocks (2 per thread).
__global__ void k_scan_col(const unsigned* __restrict__ blockHist,
                           unsigned* __restrict__ blockOfs,
                           unsigned* __restrict__ total, int NA) {
    int k = blockIdx.x, t = threadIdx.x;           // 256 threads
    unsigned v[2], s = 0;
    #pragma unroll
    for (int i = 0; i < 2; ++i) {
        int blk = 2 * t + i;
        v[i] = (blk < NA) ? blockHist[(size_t)blk * NBP + k] : 0;
        s += v[i];
    }
    __shared__ unsigned sums[256];
    sums[t] = s;
    __syncthreads();
    for (int off = 1; off < 256; off <<= 1) {
        unsigned x = (t >= off) ? sums[t - off] : 0;
        __syncthreads();
        sums[t] += x;
        __syncthreads();
    }
    unsigned run = sums[t] - s;
    #pragma unroll
    for (int i = 0; i < 2; ++i) {
        int blk = 2 * t + i;
        if (blk < NA) blockOfs[(size_t)blk * NBP + k] = run;
        run += v[i];
    }
    if (t == 255) total[k] = sums[t];
}

// A2b: exclusive scan of bucket totals -> base[0..nb], base[nb]=E.
__global__ void k_scan_base(const unsigned* __restrict__ total,
                            unsigned* __restrict__ base, int nb) {
    __shared__ unsigned s[512];
    int t = threadIdx.x;                            // 512 threads
    unsigned v = (t < nb) ? total[t] : 0;
    s[t] = v;
    __syncthreads();
    for (int off = 1; off < 512; off <<= 1) {
        unsigned x = (t >= off) ? s[t - off] : 0;
        __syncthreads();
        s[t] += x;
        __syncthreads();
    }
    if (t < nb) base[t] = s[t] - v;
    if (t == nb - 1) base[nb] = s[t];
}

// A3: scatter packed (src<<SH|dlo) into bucket segments (plain stores).
__global__ void k_bin(const int* __restrict__ src, const int* __restrict__ dst,
                      int E, const unsigned* __restrict__ base,
                      const unsigned* __restrict__ blockOfs,
                      unsigned* __restrict__ epack) {
    __shared__ unsigned cur[NBP];
    int b = blockIdx.x, t = threadIdx.x;
    for (int i = t; i < NBP; i += BS)
        cur[i] = base[i] + blockOfs[(size_t)b * NBP + i];
    __syncthreads();
    int lo = b * CH, hi = min(E, lo + CH);
    for (int i = lo + t; i < hi; i += BS) {
        unsigned d = (unsigned)dst[i];
        unsigned pos = atomicAdd(&cur[d >> SH], 1u);
        epack[pos] = ((unsigned)src[i] << SH) | (d & (NBW - 1u));
    }
}

// B: per bucket (512 nodes, 512 threads) — stage segment in LDS, count per
// node, scan -> rowofs, counting-sort in place, emit dinv / x_scaled.
__global__ void k_build(unsigned* __restrict__ epack, const unsigned* __restrict__ base,
                        const float* __restrict__ x,
                        float* __restrict__ dinv, float* __restrict__ x_scaled,
                        unsigned* __restrict__ rowofs, int N) {
    __shared__ unsigned stage[CAP];
    __shared__ unsigned cnt[NBW];
    __shared__ unsigned sc[NBW];
    __shared__ unsigned cur[NBW];
    int k = blockIdx.x, t = threadIdx.x;           // 512 threads
    unsigned lo = base[k], hi = base[k + 1];
    int len = (int)(hi - lo);                       // <= CAP
    for (int i = t; i < len; i += NBW) stage[i] = epack[lo + i];
    cnt[t] = 0;
    __syncthreads();
    for (int i = t; i < len; i += NBW) atomicAdd(&cnt[stage[i] & (NBW - 1u)], 1u);
    __syncthreads();
    sc[t] = cnt[t];
    __syncthreads();
    for (int off = 1; off < NBW; off <<= 1) {
        unsigned v = (t >= off) ? sc[t - off] : 0;
        __syncthreads();
        sc[t] += v;
        __syncthreads();
    }
    unsigned excl = sc[t] - cnt[t];
    cur[t] = excl;
    int node = k * NBW + t;
    if (node <= N) rowofs[node] = lo + excl;       // node==N lands at E
    if (node < N) {
        float di = rsqrtf((float)(cnt[t] + 1));    // +1: self loop
        dinv[node] = di;
        float4 xv = ((const float4*)x)[node];
        ((float4*)x_scaled)[node] = make_float4(xv.x * di, xv.y * di, xv.z * di, xv.w * di);
    }
    __syncthreads();
    for (int i = t; i < len; i += NBW) {
        unsigned p = stage[i];
        unsigned pos = atomicAdd(&cur[p & (NBW - 1u)], 1u);
        epack[lo + pos] = p >> SH;                 // sorted src, in place (reads
    }                                              // all went through LDS stage)
}

// C1: pull-mode layer-1 aggregation + fused node math (no atomics).
__global__ void k_agg1(const unsigned* __restrict__ esorted, const unsigned* __restrict__ rowofs,
                       const float* __restrict__ x_scaled, const float* __restrict__ dinv,
                       const float* __restrict__ W1, const float* __restrict__ b1,
                       const float* __restrict__ W2,
                       float* __restrict__ z_scaled, int N) {
    int node = blockIdx.x * blockDim.x + threadIdx.x;
    if (node >= N) return;
    unsigned lo = rowofs[node], hi = rowofs[node + 1];
    const float4* xs4 = (const float4*)x_scaled;
    float4 a0 = xs4[node];                          // self loop
    float4 a1 = make_float4(0.f, 0.f, 0.f, 0.f);
    unsigned i = lo;
    for (; i + 1 < hi; i += 2) {                    // 2 independent chains
        unsigned s0 = esorted[i], s1 = esorted[i + 1];
        float4 v0 = xs4[s0], v1 = xs4[s1];
        a0.x += v0.x; a0.y += v0.y; a0.z += v0.z; a0.w += v0.w;
        a1.x += v1.x; a1.y += v1.y; a1.z += v1.z; a1.w += v1.w;
    }
    if (i < hi) {
        float4 v = xs4[esorted[i]];
        a0.x += v.x; a0.y += v.y; a0.z += v.z; a0.w += v.w;
    }
    float di = dinv[node];
    float p0 = di * (a0.x + a1.x);
    float p1 = di * (a0.y + a1.y);
    float p2 = di * (a0.z + a1.z);
    float p3 = di * (a0.w + a1.w);
    float z = 0.0f;
    #pragma unroll
    for (int c = 0; c < 16; ++c) {
        float h1 = p0 * W1[0 * 16 + c] + p1 * W1[1 * 16 + c]
                 + p2 * W1[2 * 16 + c] + p3 * W1[3 * 16 + c] + b1[c];
        h1 = fmaxf(h1, 0.0f);
        z += h1 * W2[c];
    }
    z_scaled[node] = z * di;
}

// C2: pull-mode layer-2 aggregation (no atomics).
__global__ void k_agg2(const unsigned* __restrict__ esorted, const unsigned* __restrict__ rowofs,
                       const float* __restrict__ z_scaled, const float* __restrict__ dinv,
                       const float* __restrict__ b2, float* __restrict__ out, int N) {
    int node = blockIdx.x * blockDim.x + threadIdx.x;
    if (node >= N) return;
    unsigned lo = rowofs[node], hi = rowofs[node + 1];
    float a0 = z_scaled[node];                      // self loop
    float a1 = 0.0f;
    unsigned i = lo;
    for (; i + 1 < hi; i += 2) {
        float v0 = z_scaled[esorted[i]], v1 = z_scaled[esorted[i + 1]];
        a0 += v0; a1 += v1;
    }
    if (i < hi) a0 += z_scaled[esorted[i]];
    out[node] = dinv[node] * (a0 + a1) + b2[0];
}

extern "C" void kernel_launch(void* const* d_in, const int* in_sizes, int n_in,
                              void* d_out, int out_size, void* d_ws, size_t ws_size,
                              hipStream_t stream) {
    const float* x  = (const float*)d_in[0];
    const int*   ei = (const int*)d_in[1];   // [2, E] as int32
    const float* W1 = (const float*)d_in[2];
    const float* b1 = (const float*)d_in[3];
    const float* W2 = (const float*)d_in[4];
    const float* b2 = (const float*)d_in[5];

    const int N = in_sizes[0] / 4;
    const int E = in_sizes[1] / 2;
    const int* src = ei;
    const int* dst = ei + E;
    const int nb = (N + NBW - 1) / NBW;      // 391
    const int NA = (E + CH - 1) / CH;        // 391

    // Workspace (~20 MB): blockHist[NA*NBP] | blockOfs[NA*NBP] | total[NBP] |
    //   base[NBP+1] | epack[E] | rowofs[N+1] | dinv[N] | x_scaled[N*4] | z_scaled[N]
    char* ws = (char*)d_ws;
    unsigned* blockHist = (unsigned*)ws;  ws += (size_t)NA * NBP * 4;
    unsigned* blockOfs  = (unsigned*)ws;  ws += (size_t)NA * NBP * 4;
    unsigned* total     = (unsigned*)ws;  ws += (size_t)NBP * 4;
    unsigned* base      = (unsigned*)ws;  ws += (size_t)(NBP + 1) * 4;
    unsigned* epack     = (unsigned*)ws;  ws += (size_t)E * 4;
    unsigned* rowofs    = (unsigned*)ws;  ws += (size_t)(N + 1) * 4;
    float*    dinv      = (float*)ws;     ws += (size_t)N * 4;
    float*    x_scaled  = (float*)ws;     ws += (size_t)N * 4 * 4;
    float*    z_scaled  = (float*)ws;     ws += (size_t)N * 4;
    float* out = (float*)d_out;

    k_hist     <<<NA, BS, 0, stream>>>(dst, E, blockHist);
    k_scan_col <<<nb, 256, 0, stream>>>(blockHist, blockOfs, total, NA);
    k_scan_base<<<1, 512, 0, stream>>>(total, base, nb);
    k_bin      <<<NA, BS, 0, stream>>>(src, dst, E, base, blockOfs, epack);
    k_build    <<<nb, NBW, 0, stream>>>(epack, base, x, dinv, x_scaled, rowofs, N);
    k_agg1     <<<(N + 255) / 256, 256, 0, stream>>>(epack, rowofs, x_scaled, dinv, W1, b1, W2, z_scaled, N);
    k_agg2     <<<(N + 255) / 256, 256, 0, stream>>>(epack, rowofs, z_scaled, dinv, b2, out, N);
}